// Round 1
// baseline (230.896 us; speedup 1.0000x reference)
//
#include <hip/hip_runtime.h>
#include <math.h>

namespace {
constexpr int N_ = 2048;
constexpr int D_ = 128;
constexpr int K_ = 8;
constexpr int M_ = 64;
constexpr float JIT = 1e-5f;
constexpr float L2E = 1.4426950408889634f;

// ws layout (float offsets)
constexpr int OFF_ARR2 = 0;                   // N*16  : per-n [a[8], ib2s[8]]
constexpr int OFF_C2   = N_ * 16;             // N     : prod rsqrt(2s2+1)
constexpr int OFF_ARR1 = N_ * 17;             // N*16  : per-n [a[8], ib1s[8]]
constexpr int OFF_CY   = N_ * 33;             // N     : prod rsqrt(1+s2) * Y[n]
constexpr int OFF_P2P  = N_ * 34;             // 16*4096 : psi2 partial sums
constexpr int OFF_P1Y  = N_ * 34 + 16 * 4096; // 8*64    : Psi1^T Y partials
}

struct F8 { float f[8]; };

// ---------------------------------------------------------------------------
// Kernel 1: per-n statistics  a[k] = q_mu[k]·x_n,  s2[k] = q_cov[k]·(x_n^2)
// ---------------------------------------------------------------------------
__global__ __launch_bounds__(256) void vdmgp_prep(
    const float* __restrict__ X, const float* __restrict__ Y,
    const float* __restrict__ qmu, const float* __restrict__ qcov,
    float* __restrict__ ws) {
  __shared__ float smu[D_ * K_];   // transposed: [d][k]
  __shared__ float scov[D_ * K_];
  const int tid = threadIdx.x;
  for (int idx = tid; idx < K_ * D_; idx += 256) {
    int k = idx >> 7, d = idx & 127;
    smu[d * K_ + k]  = qmu[idx];
    scov[d * K_ + k] = qcov[idx];
  }
  __syncthreads();

  const int n = blockIdx.x * 256 + tid;
  float a[K_], s2[K_];
#pragma unroll
  for (int k = 0; k < K_; k++) { a[k] = 0.f; s2[k] = 0.f; }

  const float4* xrow = reinterpret_cast<const float4*>(X + n * D_);
  for (int dq = 0; dq < D_ / 4; dq++) {
    float4 xv = xrow[dq];
    float xs[4] = {xv.x, xv.y, xv.z, xv.w};
#pragma unroll
    for (int t = 0; t < 4; t++) {
      const int d = dq * 4 + t;
      const float x = xs[t];
      const float xx = x * x;
      F8 mu = *reinterpret_cast<const F8*>(&smu[d * K_]);
      F8 cv = *reinterpret_cast<const F8*>(&scov[d * K_]);
#pragma unroll
      for (int k = 0; k < K_; k++) {
        a[k]  = fmaf(mu.f[k], x, a[k]);
        s2[k] = fmaf(cv.f[k], xx, s2[k]);
      }
    }
  }

  float* arr2 = ws + OFF_ARR2;
  float* c2   = ws + OFF_C2;
  float* arr1 = ws + OFF_ARR1;
  float* cy   = ws + OFF_CY;
  float prod2 = 1.f, prod1 = 1.f;
#pragma unroll
  for (int k = 0; k < K_; k++) {
    const float b2 = 2.f * s2[k] + 1.f;
    const float b1 = 1.f + s2[k];
    arr2[n * 16 + k]     = a[k];
    arr2[n * 16 + 8 + k] = L2E / b2;          // exp(-t^2/b2) = exp2(-t^2 * L2E/b2)
    arr1[n * 16 + k]     = a[k];
    arr1[n * 16 + 8 + k] = 0.5f * L2E / b1;   // exp(-0.5 t^2/b1)
    prod2 *= rsqrtf(b2);
    prod1 *= rsqrtf(b1);
  }
  c2[n] = prod2;
  cy[n] = prod1 * Y[n];
}

// ---------------------------------------------------------------------------
// Kernel 2: psi2 partial sums over n-chunks.
// grid (16 pair-blocks, 16 n-chunks); thread owns one (i,j) pair.
// ---------------------------------------------------------------------------
__global__ __launch_bounds__(256) void vdmgp_psi2(
    const float* __restrict__ Z, const float* __restrict__ ws,
    float* __restrict__ part) {
  __shared__ float sa[128 * 16];
  __shared__ float sc[128];
  const int tid = threadIdx.x;
  const int pair = blockIdx.x * 256 + tid;
  const int i = pair >> 6, j = pair & 63;

  float zb[K_];
#pragma unroll
  for (int k = 0; k < K_; k++) zb[k] = 0.5f * (Z[i * K_ + k] + Z[j * K_ + k]);

  const int nbase = blockIdx.y * 128;
  const float4* src = reinterpret_cast<const float4*>(ws + OFF_ARR2 + nbase * 16);
  float4* dst = reinterpret_cast<float4*>(sa);
  for (int idx = tid; idx < 128 * 4; idx += 256) dst[idx] = src[idx];
  if (tid < 128) sc[tid] = (ws + OFF_C2)[nbase + tid];
  __syncthreads();

  float acc = 0.f;
  for (int nl = 0; nl < 128; nl++) {
    const F8 av = *reinterpret_cast<const F8*>(&sa[nl * 16]);
    const F8 ib = *reinterpret_cast<const F8*>(&sa[nl * 16 + 8]);
    float s = 0.f;
#pragma unroll
    for (int k = 0; k < K_; k++) {
      const float t = av.f[k] - zb[k];
      s = fmaf(t * t, ib.f[k], s);
    }
    acc = fmaf(sc[nl], exp2f(-s), acc);
  }
  part[blockIdx.y * 4096 + pair] = acc;
}

// ---------------------------------------------------------------------------
// Kernel 3: Psi1^T Y partials. grid 8 (n-chunks of 256); thread -> (m, stripe)
// ---------------------------------------------------------------------------
__global__ __launch_bounds__(256) void vdmgp_psi1y(
    const float* __restrict__ Z, const float* __restrict__ ws,
    float* __restrict__ p1y) {
  __shared__ float sa[256 * 16];
  __shared__ float scy[256];
  __shared__ float red[256];
  const int tid = threadIdx.x;
  const int m = tid & 63;
  const int stripe = tid >> 6;

  float zm[K_];
#pragma unroll
  for (int k = 0; k < K_; k++) zm[k] = Z[m * K_ + k];

  const int nbase = blockIdx.x * 256;
  const float4* src = reinterpret_cast<const float4*>(ws + OFF_ARR1 + nbase * 16);
  float4* dst = reinterpret_cast<float4*>(sa);
  for (int idx = tid; idx < 256 * 4; idx += 256) dst[idx] = src[idx];
  scy[tid] = (ws + OFF_CY)[nbase + tid];
  __syncthreads();

  float acc = 0.f;
  for (int t = 0; t < 64; t++) {
    const int nl = stripe * 64 + t;
    const F8 av = *reinterpret_cast<const F8*>(&sa[nl * 16]);
    const F8 ib = *reinterpret_cast<const F8*>(&sa[nl * 16 + 8]);
    float s = 0.f;
#pragma unroll
    for (int k = 0; k < K_; k++) {
      const float d = av.f[k] - zm[k];
      s = fmaf(d * d, ib.f[k], s);
    }
    acc = fmaf(scy[nl], exp2f(-s), acc);
  }
  red[tid] = acc;
  __syncthreads();
  if (tid < 64)
    p1y[blockIdx.x * 64 + tid] = red[tid] + red[64 + tid] + red[128 + tid] + red[192 + tid];
}

// ---------------------------------------------------------------------------
// Kernel 4: everything small. 1 block, 256 threads.
// ---------------------------------------------------------------------------
__global__ __launch_bounds__(256) void vdmgp_final(
    const float* __restrict__ Y,
    const float* __restrict__ qmu, const float* __restrict__ qcov,
    const float* __restrict__ Z,
    const float* __restrict__ sfp, const float* __restrict__ nvp,
    const float* __restrict__ ws, float* __restrict__ out) {
  __shared__ float L1s[M_][M_ + 1];   // Kuu -> chol
  __shared__ float L2s[M_][M_ + 1];   // sigma2*Kuu + psi2 + jitter -> chol
  __shared__ float P2s[M_][M_ + 1];   // psi2 -> B -> C
  __shared__ float zl[M_][K_];
  __shared__ float pys[M_];
  __shared__ float red[256];
  __shared__ float dinv[2];
  __shared__ float d1inv[M_];
  __shared__ float scal[8];

  const int tid = threadIdx.x;
  const float sf = sfp[0];
  const float s2v = nvp[0];
  const float* p2p = ws + OFF_P2P;
  const float* p1y = ws + OFF_P1Y;

  if (tid < M_) {
#pragma unroll
    for (int k = 0; k < K_; k++) zl[tid][k] = Z[tid * K_ + k];
  }
  __syncthreads();

  // Kuu, left*sum(right), KuPsi2
  for (int p = tid; p < M_ * M_; p += 256) {
    const int i = p >> 6, j = p & 63;
    float sq = 0.f;
#pragma unroll
    for (int k = 0; k < K_; k++) { const float d = zl[i][k] - zl[j][k]; sq = fmaf(d, d, sq); }
    const float kuu = exp2f(-0.5f * L2E * sq);
    const float lft = sf * sf * exp2f(-0.25f * L2E * sq);
    float sr = 0.f;
#pragma unroll
    for (int c = 0; c < 16; c++) sr += p2p[c * 4096 + p];
    const float psi2 = lft * sr;
    const float jit = (i == j) ? JIT : 0.f;
    const float kj = kuu + jit;
    L1s[i][j] = kj;
    P2s[i][j] = psi2;
    L2s[i][j] = fmaf(s2v, kj, psi2 + jit);
  }
  if (tid < M_) {
    float s = 0.f;
#pragma unroll
    for (int b = 0; b < 8; b++) s += p1y[b * M_ + tid];
    pys[tid] = sf * s;
  }
  // YY
  float yy = 0.f;
  for (int n = tid; n < N_; n += 256) { const float y = Y[n]; yy = fmaf(y, y, yy); }
  red[tid] = yy;
  __syncthreads();
  for (int s = 128; s > 0; s >>= 1) { if (tid < s) red[tid] += red[tid + s]; __syncthreads(); }
  if (tid == 0) scal[0] = red[0];
  __syncthreads();

  // KL
  float klp = 0.f;
  if (tid < K_) {
    float slog = 0.f, srow = 0.f;
    for (int d = 0; d < D_; d++) {
      const float qc = qcov[tid * D_ + d];
      const float qm = qmu[tid * D_ + d];
      slog += logf(qc);
      srow += qc + qm * qm;
    }
    klp = slog - (float)D_ * logf(srow) + (float)D_ * logf((float)D_);
  }
  red[tid] = klp;
  __syncthreads();
  if (tid == 0) {
    float s = 0.f;
    for (int k = 0; k < K_; k++) s += red[k];
    scal[1] = s;
  }
  __syncthreads();

  // Cholesky of L1s (wave containing tid<64) and L2s (tid in [64,128)) together
  {
    const int i = tid & 63;
    const int mat = tid >> 6;
    for (int jc = 0; jc < M_; jc++) {
      float tval = 0.f;
      if (mat < 2 && i >= jc) {
        float (*L)[M_ + 1] = (mat == 0) ? L1s : L2s;
        float s = L[i][jc];
        for (int p = 0; p < jc; p++) s = fmaf(-L[i][p], L[jc][p], s);
        tval = s;
        if (i == jc) {
          const float dsq = sqrtf(s);
          L[jc][jc] = dsq;
          const float iv = 1.0f / dsq;
          dinv[mat] = iv;
          if (mat == 0) d1inv[jc] = iv;
        }
      }
      __syncthreads();
      if (mat < 2 && i > jc) {
        float (*L)[M_ + 1] = (mat == 0) ? L1s : L2s;
        L[i][jc] = tval * dinv[mat];
      }
      __syncthreads();
    }
  }

  // logdet(Kuu) - logdet(KuPsi2)
  red[tid] = (tid < M_) ? 2.f * (logf(L1s[tid][tid]) - logf(L2s[tid][tid])) : 0.f;
  __syncthreads();
  for (int s = 128; s > 0; s >>= 1) { if (tid < s) red[tid] += red[tid + s]; __syncthreads(); }
  if (tid == 0) scal[2] = red[0];
  __syncthreads();

  // quad = || L2^{-1} pys ||^2  (wave 0, shfl column sweep)
  if (tid < M_) {
    float pv = pys[tid];
    const int i = tid;
    for (int p = 0; p < M_; p++) {
      const float lpp = L2s[p][p];
      const float vcur = __shfl(pv, p, 64);
      const float val = vcur / lpp;
      if (i == p) pv = val;
      else if (i > p) pv = fmaf(-L2s[i][p], val, pv);
    }
    float q = pv * pv;
#pragma unroll
    for (int off = 32; off > 0; off >>= 1) q += __shfl_down(q, off, 64);
    if (tid == 0) scal[3] = q;
  }
  __syncthreads();

  // trace(Kuu^{-1} psi2): per-column forward then backward substitution (wave 0)
  if (tid < M_) {
    const int c = tid;
    for (int p = 0; p < M_; p++) {
      const float bp = P2s[p][c] * d1inv[p];
      P2s[p][c] = bp;
      for (int i2 = p + 1; i2 < M_; i2++)
        P2s[i2][c] = fmaf(-L1s[i2][p], bp, P2s[i2][c]);
    }
    for (int p = M_ - 1; p >= 0; p--) {
      const float cp = P2s[p][c] * d1inv[p];
      P2s[p][c] = cp;
      for (int i2 = 0; i2 < p; i2++)
        P2s[i2][c] = fmaf(-L1s[p][i2], cp, P2s[i2][c]);
    }
    float tr = P2s[c][c];
#pragma unroll
    for (int off = 32; off > 0; off >>= 1) tr += __shfl_down(tr, off, 64);
    if (tid == 0) scal[4] = tr;
  }
  __syncthreads();

  if (tid == 0) {
    const float YY = scal[0], KL = scal[1], ldd = scal[2], quad = scal[3], tr = scal[4];
    const float inv_s2 = 1.0f / s2v;
    const float F1 = -(float)N_ * logf(6.283185307179586f)
                   - (float)(N_ - M_) * logf(s2v)
                   + ldd
                   - YY * inv_s2
                   + quad * inv_s2
                   - (float)N_ * sf * sf * inv_s2
                   + tr * inv_s2;
    out[0] = 0.5f * (F1 + KL);
  }
}

extern "C" void kernel_launch(void* const* d_in, const int* in_sizes, int n_in,
                              void* d_out, int out_size, void* d_ws, size_t ws_size,
                              hipStream_t stream) {
  const float* X    = (const float*)d_in[0];
  const float* Y    = (const float*)d_in[1];
  const float* qmu  = (const float*)d_in[2];
  const float* qcov = (const float*)d_in[3];
  const float* Z    = (const float*)d_in[4];
  const float* sfp  = (const float*)d_in[5];
  const float* nvp  = (const float*)d_in[6];
  float* ws  = (float*)d_ws;
  float* out = (float*)d_out;

  vdmgp_prep<<<8, 256, 0, stream>>>(X, Y, qmu, qcov, ws);
  vdmgp_psi2<<<dim3(16, 16), 256, 0, stream>>>(Z, ws, ws + OFF_P2P);
  vdmgp_psi1y<<<8, 256, 0, stream>>>(Z, ws, ws + OFF_P1Y);
  vdmgp_final<<<1, 256, 0, stream>>>(Y, qmu, qcov, Z, sfp, nvp, ws, out);
}

// Round 2
// 74.681 us; speedup vs baseline: 3.0917x; 3.0917x over previous
//
#include <hip/hip_runtime.h>
#include <math.h>

namespace {
constexpr int N_ = 2048;
constexpr int D_ = 128;
constexpr int K_ = 8;
constexpr int M_ = 64;
constexpr float JIT = 1e-5f;
constexpr float L2E = 1.4426950408889634f;
constexpr float LN2 = 0.6931471805599453f;

// ws layout (float offsets)
constexpr int OFF_ARR2 = 0;                   // N*16  : per-n [a[8], ib2s[8]]
constexpr int OFF_C2   = N_ * 16;             // N     : prod rsqrt(2s2+1)
constexpr int OFF_ARR1 = N_ * 17;             // N*16  : per-n [a[8], ib1s[8]]
constexpr int OFF_CY   = N_ * 33;             // N     : prod rsqrt(1+s2) * Y[n]
constexpr int OFF_P2P  = N_ * 34;             // 16*4096 : psi2 partial sums
constexpr int OFF_P1Y  = N_ * 34 + 16 * 4096; // 8*64    : Psi1^T Y partials
constexpr int OFF_PSI2 = OFF_P1Y + 512;       // 4096    : reduced psi2 (left folded)
}

struct F8 { float f[8]; };

// ---------------------------------------------------------------------------
// Kernel 1: per-n statistics  a[k] = q_mu[k]·x_n,  s2[k] = q_cov[k]·(x_n^2)
// ---------------------------------------------------------------------------
__global__ __launch_bounds__(256) void vdmgp_prep(
    const float* __restrict__ X, const float* __restrict__ Y,
    const float* __restrict__ qmu, const float* __restrict__ qcov,
    float* __restrict__ ws) {
  __shared__ float smu[D_ * K_];   // transposed: [d][k]
  __shared__ float scov[D_ * K_];
  const int tid = threadIdx.x;
  for (int idx = tid; idx < K_ * D_; idx += 256) {
    int k = idx >> 7, d = idx & 127;
    smu[d * K_ + k]  = qmu[idx];
    scov[d * K_ + k] = qcov[idx];
  }
  __syncthreads();

  const int n = blockIdx.x * 256 + tid;
  float a[K_], s2[K_];
#pragma unroll
  for (int k = 0; k < K_; k++) { a[k] = 0.f; s2[k] = 0.f; }

  const float4* xrow = reinterpret_cast<const float4*>(X + n * D_);
  for (int dq = 0; dq < D_ / 4; dq++) {
    float4 xv = xrow[dq];
    float xs[4] = {xv.x, xv.y, xv.z, xv.w};
#pragma unroll
    for (int t = 0; t < 4; t++) {
      const int d = dq * 4 + t;
      const float x = xs[t];
      const float xx = x * x;
      F8 mu = *reinterpret_cast<const F8*>(&smu[d * K_]);
      F8 cv = *reinterpret_cast<const F8*>(&scov[d * K_]);
#pragma unroll
      for (int k = 0; k < K_; k++) {
        a[k]  = fmaf(mu.f[k], x, a[k]);
        s2[k] = fmaf(cv.f[k], xx, s2[k]);
      }
    }
  }

  float* arr2 = ws + OFF_ARR2;
  float* c2   = ws + OFF_C2;
  float* arr1 = ws + OFF_ARR1;
  float* cy   = ws + OFF_CY;
  float prod2 = 1.f, prod1 = 1.f;
#pragma unroll
  for (int k = 0; k < K_; k++) {
    const float b2 = 2.f * s2[k] + 1.f;
    const float b1 = 1.f + s2[k];
    arr2[n * 16 + k]     = a[k];
    arr2[n * 16 + 8 + k] = L2E / b2;          // exp(-t^2/b2) = exp2(-t^2 * L2E/b2)
    arr1[n * 16 + k]     = a[k];
    arr1[n * 16 + 8 + k] = 0.5f * L2E / b1;   // exp(-0.5 t^2/b1)
    prod2 *= rsqrtf(b2);
    prod1 *= rsqrtf(b1);
  }
  c2[n] = prod2;
  cy[n] = prod1 * Y[n];
}

// ---------------------------------------------------------------------------
// Kernel 2: psi2 partial sums over n-chunks.
// ---------------------------------------------------------------------------
__global__ __launch_bounds__(256) void vdmgp_psi2(
    const float* __restrict__ Z, const float* __restrict__ ws,
    float* __restrict__ part) {
  __shared__ float sa[128 * 16];
  __shared__ float sc[128];
  const int tid = threadIdx.x;
  const int pair = blockIdx.x * 256 + tid;
  const int i = pair >> 6, j = pair & 63;

  float zb[K_];
#pragma unroll
  for (int k = 0; k < K_; k++) zb[k] = 0.5f * (Z[i * K_ + k] + Z[j * K_ + k]);

  const int nbase = blockIdx.y * 128;
  const float4* src = reinterpret_cast<const float4*>(ws + OFF_ARR2 + nbase * 16);
  float4* dst = reinterpret_cast<float4*>(sa);
  for (int idx = tid; idx < 128 * 4; idx += 256) dst[idx] = src[idx];
  if (tid < 128) sc[tid] = (ws + OFF_C2)[nbase + tid];
  __syncthreads();

  float acc = 0.f;
  for (int nl = 0; nl < 128; nl++) {
    const F8 av = *reinterpret_cast<const F8*>(&sa[nl * 16]);
    const F8 ib = *reinterpret_cast<const F8*>(&sa[nl * 16 + 8]);
    float s = 0.f;
#pragma unroll
    for (int k = 0; k < K_; k++) {
      const float t = av.f[k] - zb[k];
      s = fmaf(t * t, ib.f[k], s);
    }
    acc = fmaf(sc[nl], exp2f(-s), acc);
  }
  part[blockIdx.y * 4096 + pair] = acc;
}

// ---------------------------------------------------------------------------
// Kernel 3: Psi1^T Y partials.
// ---------------------------------------------------------------------------
__global__ __launch_bounds__(256) void vdmgp_psi1y(
    const float* __restrict__ Z, const float* __restrict__ ws,
    float* __restrict__ p1y) {
  __shared__ float sa[256 * 16];
  __shared__ float scy[256];
  __shared__ float red[256];
  const int tid = threadIdx.x;
  const int m = tid & 63;
  const int stripe = tid >> 6;

  float zm[K_];
#pragma unroll
  for (int k = 0; k < K_; k++) zm[k] = Z[m * K_ + k];

  const int nbase = blockIdx.x * 256;
  const float4* src = reinterpret_cast<const float4*>(ws + OFF_ARR1 + nbase * 16);
  float4* dst = reinterpret_cast<float4*>(sa);
  for (int idx = tid; idx < 256 * 4; idx += 256) dst[idx] = src[idx];
  scy[tid] = (ws + OFF_CY)[nbase + tid];
  __syncthreads();

  float acc = 0.f;
  for (int t = 0; t < 64; t++) {
    const int nl = stripe * 64 + t;
    const F8 av = *reinterpret_cast<const F8*>(&sa[nl * 16]);
    const F8 ib = *reinterpret_cast<const F8*>(&sa[nl * 16 + 8]);
    float s = 0.f;
#pragma unroll
    for (int k = 0; k < K_; k++) {
      const float d = av.f[k] - zm[k];
      s = fmaf(d * d, ib.f[k], s);
    }
    acc = fmaf(scy[nl], exp2f(-s), acc);
  }
  red[tid] = acc;
  __syncthreads();
  if (tid < 64)
    p1y[blockIdx.x * 64 + tid] = red[tid] + red[64 + tid] + red[128 + tid] + red[192 + tid];
}

// ---------------------------------------------------------------------------
// Kernel 4 (new): reduce psi2 partials over the 16 n-chunks, fold `left`.
// 16 blocks x 256 threads, one thread per (i,j) pair.
// ---------------------------------------------------------------------------
__global__ __launch_bounds__(256) void vdmgp_reduce(
    const float* __restrict__ Z, const float* __restrict__ sfp,
    float* __restrict__ ws) {
  const int tid = threadIdx.x;
  const int pair = blockIdx.x * 256 + tid;
  const int i = pair >> 6, j = pair & 63;
  const float sf = sfp[0];
  float sq = 0.f;
#pragma unroll
  for (int k = 0; k < K_; k++) {
    const float d = Z[i * K_ + k] - Z[j * K_ + k];
    sq = fmaf(d, d, sq);
  }
  const float lft = sf * sf * exp2f(-0.25f * L2E * sq);
  const float* p2p = ws + OFF_P2P;
  float sr = 0.f;
#pragma unroll
  for (int c = 0; c < 16; c++) sr += p2p[c * 4096 + pair];
  ws[OFF_PSI2 + pair] = lft * sr;
}

// ---------------------------------------------------------------------------
// Kernel 5: final. Two symmetric sweep (Gauss-Jordan) inversions in registers
// (wave 0: Kuu+jit, wave 1: KuPsi2), no barriers inside; waves 2/3 do YY+KL.
// ---------------------------------------------------------------------------
__global__ __launch_bounds__(256) void vdmgp_final(
    const float* __restrict__ Y,
    const float* __restrict__ qmu, const float* __restrict__ qcov,
    const float* __restrict__ Z,
    const float* __restrict__ sfp, const float* __restrict__ nvp,
    const float* __restrict__ ws, float* __restrict__ out) {
  __shared__ float P2s[M_][M_ + 1];            // psi2, padded
  __shared__ float zl[M_][9];                  // Z, padded
  __shared__ float pysL[M_];                   // Psi1^T Y
  __shared__ __align__(16) float rowbuf[2][2][M_];  // [wave][parity][64]
  __shared__ float scal[8];

  const int tid = threadIdx.x;
  const int lane = tid & 63;
  const int wave = tid >> 6;
  const float sf = sfp[0];
  const float s2v = nvp[0];

  // ---- phase 0: cooperative loads ----
  const float* psi2 = ws + OFF_PSI2;
#pragma unroll
  for (int t = 0; t < 16; t++) {
    const int idx = t * 256 + tid;
    P2s[idx >> 6][idx & 63] = psi2[idx];
  }
  for (int idx = tid; idx < M_ * K_; idx += 256) zl[idx >> 3][idx & 7] = Z[idx];
  if (tid < M_) {
    const float* p1y = ws + OFF_P1Y;
    float s = 0.f;
#pragma unroll
    for (int b = 0; b < 8; b++) s += p1y[b * M_ + tid];
    pysL[tid] = sf * s;
  }
  __syncthreads();

  // ---- phase 1: no cross-wave sync; each wave owns its job ----
  if (wave < 2) {
    const bool isA2 = (wave == 1);
    float zj[K_];
#pragma unroll
    for (int k = 0; k < K_; k++) zj[k] = zl[lane][k];

    // build column `lane` of A (symmetric) in registers
    float reg[M_];
#pragma unroll
    for (int i = 0; i < M_; i++) {
      float sq = 0.f;
#pragma unroll
      for (int k = 0; k < K_; k++) { const float dd = zl[i][k] - zj[k]; sq = fmaf(dd, dd, sq); }
      const float jit = (i == lane) ? JIT : 0.f;
      const float kj = exp2f(-0.5f * L2E * sq) + jit;     // Kuu + jitter
      reg[i] = isA2 ? fmaf(s2v, kj, P2s[i][lane] + jit) : kj;
    }

    // symmetric sweep: after all 64 pivots, reg[i] = (-A^{-1})[i][lane];
    // pivots d_p are the LDL^T d's -> logdet = sum log d_p.
    float ld = 0.f;
    float* rb0 = rowbuf[wave][0];
    float* rb1 = rowbuf[wave][1];
#pragma unroll
    for (int p = 0; p < M_; p++) {
      float* rb = (p & 1) ? rb1 : rb0;
      rb[lane] = reg[p];                  // row p == col p (symmetry)
      const float d = rb[p];              // pivot (wave-uniform)
      const float ipv = 1.0f / d;
      ld += __log2f(d);
      const float t = (lane == p) ? (1.f - ipv) : (reg[p] * ipv);
      const float4* rbq = reinterpret_cast<const float4*>(rb);
#pragma unroll
      for (int q = 0; q < 16; q++) {
        const float4 r4 = rbq[q];
        reg[4 * q + 0] = fmaf(-t, r4.x, reg[4 * q + 0]);
        reg[4 * q + 1] = fmaf(-t, r4.y, reg[4 * q + 1]);
        reg[4 * q + 2] = fmaf(-t, r4.z, reg[4 * q + 2]);
        reg[4 * q + 3] = fmaf(-t, r4.w, reg[4 * q + 3]);
      }
      reg[p] = (lane == p) ? (-ipv) : t;
    }

    // consume: trace (wave 0) / quadratic form (wave 1); negate for sweep sign
    float local = 0.f;
    if (!isA2) {
#pragma unroll
      for (int i = 0; i < M_; i++) local = fmaf(reg[i], P2s[i][lane], local);
    } else {
#pragma unroll
      for (int i = 0; i < M_; i++) local = fmaf(reg[i], pysL[i], local);
      local *= pysL[lane];
    }
#pragma unroll
    for (int off = 32; off > 0; off >>= 1) local += __shfl_down(local, off, 64);
    if (lane == 0) {
      scal[4 + 2 * wave] = LN2 * ld;   // [4]=logdet(Kuu), [6]=logdet(KuPsi2)
      scal[5 + 2 * wave] = -local;     // [5]=trace,       [7]=quad
    }
  } else {
    // waves 2/3: YY halves + KL rows (4 rows each, 16 lanes/row, 8 d's/lane)
    const int w = wave - 2;
    float yy = 0.f;
#pragma unroll
    for (int t = 0; t < 16; t++) {
      const float y = Y[w * 1024 + t * 64 + lane];
      yy = fmaf(y, y, yy);
    }
#pragma unroll
    for (int off = 32; off > 0; off >>= 1) yy += __shfl_down(yy, off, 64);
    if (lane == 0) scal[w] = yy;

    const int r = lane >> 4;
    const int k = w * 4 + r;
    const int d0 = (lane & 15) * 8;
    float slog = 0.f, srow = 0.f;
#pragma unroll
    for (int t = 0; t < 8; t++) {
      const float qc = qcov[k * D_ + d0 + t];
      const float qm = qmu[k * D_ + d0 + t];
      slog += logf(qc);
      srow += qc + qm * qm;
    }
#pragma unroll
    for (int off = 8; off > 0; off >>= 1) {
      slog += __shfl_down(slog, off, 16);
      srow += __shfl_down(srow, off, 16);
    }
    float klr = ((lane & 15) == 0)
        ? (slog - (float)D_ * logf(srow) + (float)D_ * logf((float)D_)) : 0.f;
#pragma unroll
    for (int off = 32; off > 0; off >>= 1) klr += __shfl_down(klr, off, 64);
    if (lane == 0) scal[2 + w] = klr;
  }
  __syncthreads();

  if (tid == 0) {
    const float YY = scal[0] + scal[1];
    const float KL = scal[2] + scal[3];
    const float ld1 = scal[4], tr = scal[5], ld2 = scal[6], quad = scal[7];
    const float inv = 1.0f / s2v;
    const float F1 = -(float)N_ * 1.8378770664093453f      // N*log(2*pi)
                   - (float)(N_ - M_) * logf(s2v)
                   + (ld1 - ld2)
                   - YY * inv
                   + quad * inv
                   - (float)N_ * sf * sf * inv
                   + tr * inv;
    out[0] = 0.5f * (F1 + KL);
  }
}

extern "C" void kernel_launch(void* const* d_in, const int* in_sizes, int n_in,
                              void* d_out, int out_size, void* d_ws, size_t ws_size,
                              hipStream_t stream) {
  const float* X    = (const float*)d_in[0];
  const float* Y    = (const float*)d_in[1];
  const float* qmu  = (const float*)d_in[2];
  const float* qcov = (const float*)d_in[3];
  const float* Z    = (const float*)d_in[4];
  const float* sfp  = (const float*)d_in[5];
  const float* nvp  = (const float*)d_in[6];
  float* ws  = (float*)d_ws;
  float* out = (float*)d_out;

  vdmgp_prep<<<8, 256, 0, stream>>>(X, Y, qmu, qcov, ws);
  vdmgp_psi2<<<dim3(16, 16), 256, 0, stream>>>(Z, ws, ws + OFF_P2P);
  vdmgp_psi1y<<<8, 256, 0, stream>>>(Z, ws, ws + OFF_P1Y);
  vdmgp_reduce<<<16, 256, 0, stream>>>(Z, sfp, ws);
  vdmgp_final<<<1, 256, 0, stream>>>(Y, qmu, qcov, Z, sfp, nvp, ws, out);
}

// Round 3
// 59.905 us; speedup vs baseline: 3.8543x; 1.2467x over previous
//
#include <hip/hip_runtime.h>
#include <math.h>

namespace {
constexpr int N_ = 2048;
constexpr int D_ = 128;
constexpr int K_ = 8;
constexpr int M_ = 64;
constexpr float JIT = 1e-5f;
constexpr float L2E = 1.4426950408889634f;
constexpr float LN2 = 0.6931471805599453f;

// ws layout (float offsets)
constexpr int OFF_ARR2 = 0;                   // N*16  : per-n [a[8], ib2s[8]]
constexpr int OFF_C2   = N_ * 16;             // N     : prod rsqrt(2s2+1)
constexpr int OFF_P2P  = N_ * 17;             // 16*4096 : psi2 partial sums
constexpr int OFF_P1Y  = N_ * 17 + 16 * 4096; // 8*64    : Psi1^T Y partials
}

struct F8 { float f[8]; };

__device__ __forceinline__ float f4e(float4 v, int e) {
  return (e == 0) ? v.x : (e == 1) ? v.y : (e == 2) ? v.z : v.w;
}

// ---------------------------------------------------------------------------
// Kernel A: per-n statistics + Psi1^T Y partials (fused; arr1/cy stay in LDS)
// 8 blocks x 256 threads; block b owns n in [256b, 256b+256).
// ---------------------------------------------------------------------------
__global__ __launch_bounds__(256) void vdmgp_prep_p1y(
    const float* __restrict__ X, const float* __restrict__ Y,
    const float* __restrict__ qmu, const float* __restrict__ qcov,
    const float* __restrict__ Z, float* __restrict__ ws) {
  __shared__ float smu[D_ * K_];   // transposed: [d][k]
  __shared__ float scov[D_ * K_];
  __shared__ float sa1[256 * 16];  // per-n [a[8], ib1s[8]]
  __shared__ float scy[256];
  __shared__ float red[256];
  const int tid = threadIdx.x;
  for (int idx = tid; idx < K_ * D_; idx += 256) {
    int k = idx >> 7, d = idx & 127;
    smu[d * K_ + k]  = qmu[idx];
    scov[d * K_ + k] = qcov[idx];
  }
  __syncthreads();

  const int n = blockIdx.x * 256 + tid;
  float a[K_], s2[K_];
#pragma unroll
  for (int k = 0; k < K_; k++) { a[k] = 0.f; s2[k] = 0.f; }

  const float4* xrow = reinterpret_cast<const float4*>(X + n * D_);
  for (int dq = 0; dq < D_ / 4; dq++) {
    float4 xv = xrow[dq];
    float xs[4] = {xv.x, xv.y, xv.z, xv.w};
#pragma unroll
    for (int t = 0; t < 4; t++) {
      const int d = dq * 4 + t;
      const float x = xs[t];
      const float xx = x * x;
      F8 mu = *reinterpret_cast<const F8*>(&smu[d * K_]);
      F8 cv = *reinterpret_cast<const F8*>(&scov[d * K_]);
#pragma unroll
      for (int k = 0; k < K_; k++) {
        a[k]  = fmaf(mu.f[k], x, a[k]);
        s2[k] = fmaf(cv.f[k], xx, s2[k]);
      }
    }
  }

  float4 w2[4];
  float prod2 = 1.f, prod1 = 1.f;
#pragma unroll
  for (int k = 0; k < K_; k++) {
    const float b2 = 2.f * s2[k] + 1.f;
    const float b1 = 1.f + s2[k];
    reinterpret_cast<float*>(w2)[k]     = a[k];
    reinterpret_cast<float*>(w2)[8 + k] = L2E / b2;   // exp(-t^2/b2) = exp2(-t^2*this)
    sa1[tid * 16 + k]     = a[k];
    sa1[tid * 16 + 8 + k] = 0.5f * L2E / b1;          // exp(-0.5 t^2/b1)
    prod2 *= rsqrtf(b2);
    prod1 *= rsqrtf(b1);
  }
  float4* arr2q = reinterpret_cast<float4*>(ws + OFF_ARR2 + n * 16);
#pragma unroll
  for (int e = 0; e < 4; e++) arr2q[e] = w2[e];
  (ws + OFF_C2)[n] = prod2;
  scy[tid] = prod1 * Y[n];
  __syncthreads();

  // Psi1^T Y over this block's 256 n's
  const int m = tid & 63;
  const int stripe = tid >> 6;
  float zm[K_];
#pragma unroll
  for (int k = 0; k < K_; k++) zm[k] = Z[m * K_ + k];

  float acc = 0.f;
  for (int t = 0; t < 64; t++) {
    const int nl = stripe * 64 + t;
    const F8 av = *reinterpret_cast<const F8*>(&sa1[nl * 16]);
    const F8 ib = *reinterpret_cast<const F8*>(&sa1[nl * 16 + 8]);
    float s = 0.f;
#pragma unroll
    for (int k = 0; k < K_; k++) {
      const float d = av.f[k] - zm[k];
      s = fmaf(d * d, ib.f[k], s);
    }
    acc = fmaf(scy[nl], exp2f(-s), acc);
  }
  red[tid] = acc;
  __syncthreads();
  if (tid < 64)
    (ws + OFF_P1Y)[blockIdx.x * 64 + tid] =
        red[tid] + red[64 + tid] + red[128 + tid] + red[192 + tid];
}

// ---------------------------------------------------------------------------
// Kernel B: psi2 partial sums over n-chunks. grid (16 pair-blocks, 16 chunks).
// ---------------------------------------------------------------------------
__global__ __launch_bounds__(256) void vdmgp_psi2(
    const float* __restrict__ Z, const float* __restrict__ ws,
    float* __restrict__ part) {
  __shared__ float sa[128 * 16];
  __shared__ float sc[128];
  const int tid = threadIdx.x;
  const int pair = blockIdx.x * 256 + tid;
  const int i = pair >> 6, j = pair & 63;

  float zb[K_];
#pragma unroll
  for (int k = 0; k < K_; k++) zb[k] = 0.5f * (Z[i * K_ + k] + Z[j * K_ + k]);

  const int nbase = blockIdx.y * 128;
  const float4* src = reinterpret_cast<const float4*>(ws + OFF_ARR2 + nbase * 16);
  float4* dst = reinterpret_cast<float4*>(sa);
  for (int idx = tid; idx < 128 * 4; idx += 256) dst[idx] = src[idx];
  if (tid < 128) sc[tid] = (ws + OFF_C2)[nbase + tid];
  __syncthreads();

  float acc = 0.f;
  for (int nl = 0; nl < 128; nl++) {
    const F8 av = *reinterpret_cast<const F8*>(&sa[nl * 16]);
    const F8 ib = *reinterpret_cast<const F8*>(&sa[nl * 16 + 8]);
    float s = 0.f;
#pragma unroll
    for (int k = 0; k < K_; k++) {
      const float t = av.f[k] - zb[k];
      s = fmaf(t * t, ib.f[k], s);
    }
    acc = fmaf(sc[nl], exp2f(-s), acc);
  }
  part[blockIdx.y * 4096 + pair] = acc;
}

// ---------------------------------------------------------------------------
// Kernel C: reduce partials (lft folded) + two 2x2-block-pivot symmetric
// sweeps in registers (wave0: Kuu, wave1: KuPsi2); waves 2/3: YY + KL.
// ---------------------------------------------------------------------------
__global__ __launch_bounds__(256, 1) void vdmgp_final(
    const float* __restrict__ Y,
    const float* __restrict__ qmu, const float* __restrict__ qcov,
    const float* __restrict__ Z,
    const float* __restrict__ sfp, const float* __restrict__ nvp,
    const float* __restrict__ ws, float* __restrict__ out) {
  __shared__ float P2s[M_][M_];                // psi2 (left folded), unpadded
  __shared__ float zl[M_][9];
  __shared__ float pysL[M_];
  __shared__ __align__(16) float rowbuf[2][2][2][M_];  // [wave][parity][A/B]
  __shared__ float scal[8];

  const int tid = threadIdx.x;
  const int lane = tid & 63;
  const int wave = tid >> 6;
  const float sf = sfp[0];
  const float s2v = nvp[0];

  // ---- phase 0 ----
  for (int idx = tid; idx < M_ * K_; idx += 256) zl[idx >> 3][idx & 7] = Z[idx];
  if (tid < M_) {
    const float* p1y = ws + OFF_P1Y;
    float s = 0.f;
#pragma unroll
    for (int b = 0; b < 8; b++) s += p1y[b * M_ + tid];
    pysL[tid] = sf * s;
  }
  __syncthreads();

  // reduce the 16 psi2 partials, fold `left`
  const float4* part4 = reinterpret_cast<const float4*>(ws + OFF_P2P);
  const float sf2 = sf * sf;
#pragma unroll
  for (int g = 0; g < 4; g++) {
    const int idx4 = g * 256 + tid;
    float4 acc = {0.f, 0.f, 0.f, 0.f};
#pragma unroll
    for (int c = 0; c < 16; c++) {
      const float4 v = part4[c * 1024 + idx4];
      acc.x += v.x; acc.y += v.y; acc.z += v.z; acc.w += v.w;
    }
    const int i = idx4 >> 4;
    const int j0 = (idx4 & 15) * 4;
    float o[4];
#pragma unroll
    for (int e = 0; e < 4; e++) {
      const int j = j0 + e;
      float sq = 0.f;
#pragma unroll
      for (int k = 0; k < K_; k++) {
        const float dd = zl[i][k] - zl[j][k];
        sq = fmaf(dd, dd, sq);
      }
      o[e] = sf2 * exp2f(-0.25f * L2E * sq) * f4e(acc, e);
    }
    *reinterpret_cast<float4*>(&P2s[i][j0]) = make_float4(o[0], o[1], o[2], o[3]);
  }
  __syncthreads();

  // ---- phase 1 ----
  if (wave < 2) {
    const bool isA2 = (wave == 1);
    float zj[K_];
#pragma unroll
    for (int k = 0; k < K_; k++) zj[k] = zl[lane][k];

    float reg[M_];
#pragma unroll
    for (int i = 0; i < M_; i++) {
      float sq = 0.f;
#pragma unroll
      for (int k = 0; k < K_; k++) { const float dd = zl[i][k] - zj[k]; sq = fmaf(dd, dd, sq); }
      const float jit = (i == lane) ? JIT : 0.f;
      const float kj = exp2f(-0.5f * L2E * sq) + jit;      // Kuu + jitter
      reg[i] = isA2 ? fmaf(s2v, kj, P2s[i][lane] + jit) : kj;
    }

    // 2x2-block symmetric sweep: reg -> (-A^{-1}) column `lane`
    float ld = 0.f;
#pragma unroll
    for (int p = 0; p < M_; p += 2) {
      const int par = (p >> 1) & 1;
      float* rbA = rowbuf[wave][par][0];
      float* rbB = rowbuf[wave][par][1];
      rbA[lane] = reg[p];
      rbB[lane] = reg[p + 1];
      float4 ra[16], rb[16];
      const float4* rbAq = reinterpret_cast<const float4*>(rbA);
      const float4* rbBq = reinterpret_cast<const float4*>(rbB);
#pragma unroll
      for (int q = 0; q < 16; q++) { ra[q] = rbAq[q]; rb[q] = rbBq[q]; }

      const float P00 = f4e(ra[p >> 2], p & 3);
      const float P01 = f4e(ra[(p + 1) >> 2], (p + 1) & 3);
      const float P11 = f4e(rb[(p + 1) >> 2], (p + 1) & 3);
      const float det = fmaf(P00, P11, -P01 * P01);
      const float idet = __builtin_amdgcn_rcpf(det);
      ld += __log2f(det);
      const float Pi00 =  P11 * idet;
      const float Pi01 = -P01 * idet;
      const float Pi11 =  P00 * idet;

      const bool isp = (lane == p), isq = (lane == p + 1);
      const float a0 = reg[p], a1 = reg[p + 1];
      const float w0 = isp ? Pi00 : (isq ? Pi01 : fmaf(Pi00, a0, Pi01 * a1));
      const float w1 = isp ? Pi01 : (isq ? Pi11 : fmaf(Pi01, a0, Pi11 * a1));
      const float t0 = isp ? (1.f - w0) : (isq ? -w0 : w0);
      const float t1 = isq ? (1.f - w1) : (isp ? -w1 : w1);
      const float f0 = (isp || isq) ? -w0 : w0;
      const float f1 = (isp || isq) ? -w1 : w1;
#pragma unroll
      for (int q = 0; q < 16; q++) {
        const float4 va = ra[q], vb = rb[q];
        reg[4 * q + 0] = fmaf(-t1, vb.x, fmaf(-t0, va.x, reg[4 * q + 0]));
        reg[4 * q + 1] = fmaf(-t1, vb.y, fmaf(-t0, va.y, reg[4 * q + 1]));
        reg[4 * q + 2] = fmaf(-t1, vb.z, fmaf(-t0, va.z, reg[4 * q + 2]));
        reg[4 * q + 3] = fmaf(-t1, vb.w, fmaf(-t0, va.w, reg[4 * q + 3]));
      }
      reg[p] = f0;
      reg[p + 1] = f1;
    }

    float local = 0.f;
    if (!isA2) {
#pragma unroll
      for (int i = 0; i < M_; i++) local = fmaf(reg[i], P2s[i][lane], local);
    } else {
#pragma unroll
      for (int i = 0; i < M_; i++) local = fmaf(reg[i], pysL[i], local);
      local *= pysL[lane];
    }
#pragma unroll
    for (int off = 32; off > 0; off >>= 1) local += __shfl_down(local, off, 64);
    if (lane == 0) {
      scal[4 + 2 * wave] = LN2 * ld;   // [4]=logdet(Kuu), [6]=logdet(KuPsi2)
      scal[5 + 2 * wave] = -local;     // [5]=trace,       [7]=quad
    }
  } else {
    const int w = wave - 2;
    float yy = 0.f;
#pragma unroll
    for (int t = 0; t < 16; t++) {
      const float y = Y[w * 1024 + t * 64 + lane];
      yy = fmaf(y, y, yy);
    }
#pragma unroll
    for (int off = 32; off > 0; off >>= 1) yy += __shfl_down(yy, off, 64);
    if (lane == 0) scal[w] = yy;

    const int r = lane >> 4;
    const int k = w * 4 + r;
    const int d0 = (lane & 15) * 8;
    float slog = 0.f, srow = 0.f;
#pragma unroll
    for (int t = 0; t < 8; t++) {
      const float qc = qcov[k * D_ + d0 + t];
      const float qm = qmu[k * D_ + d0 + t];
      slog += logf(qc);
      srow += qc + qm * qm;
    }
#pragma unroll
    for (int off = 8; off > 0; off >>= 1) {
      slog += __shfl_down(slog, off, 16);
      srow += __shfl_down(srow, off, 16);
    }
    float klr = ((lane & 15) == 0)
        ? (slog - (float)D_ * logf(srow) + (float)D_ * logf((float)D_)) : 0.f;
#pragma unroll
    for (int off = 32; off > 0; off >>= 1) klr += __shfl_down(klr, off, 64);
    if (lane == 0) scal[2 + w] = klr;
  }
  __syncthreads();

  if (tid == 0) {
    const float YY = scal[0] + scal[1];
    const float KL = scal[2] + scal[3];
    const float ld1 = scal[4], tr = scal[5], ld2 = scal[6], quad = scal[7];
    const float inv = 1.0f / s2v;
    const float F1 = -(float)N_ * 1.8378770664093453f      // N*log(2*pi)
                   - (float)(N_ - M_) * logf(s2v)
                   + (ld1 - ld2)
                   - YY * inv
                   + quad * inv
                   - (float)N_ * sf * sf * inv
                   + tr * inv;
    out[0] = 0.5f * (F1 + KL);
  }
}

extern "C" void kernel_launch(void* const* d_in, const int* in_sizes, int n_in,
                              void* d_out, int out_size, void* d_ws, size_t ws_size,
                              hipStream_t stream) {
  const float* X    = (const float*)d_in[0];
  const float* Y    = (const float*)d_in[1];
  const float* qmu  = (const float*)d_in[2];
  const float* qcov = (const float*)d_in[3];
  const float* Z    = (const float*)d_in[4];
  const float* sfp  = (const float*)d_in[5];
  const float* nvp  = (const float*)d_in[6];
  float* ws  = (float*)d_ws;
  float* out = (float*)d_out;

  vdmgp_prep_p1y<<<8, 256, 0, stream>>>(X, Y, qmu, qcov, Z, ws);
  vdmgp_psi2<<<dim3(16, 16), 256, 0, stream>>>(Z, ws, ws + OFF_P2P);
  vdmgp_final<<<1, 256, 0, stream>>>(Y, qmu, qcov, Z, sfp, nvp, ws, out);
}